// Round 11
// baseline (23811.232 us; speedup 1.0000x reference)
//
#include <hip/hip_runtime.h>
#include <stdint.h>

// ---------------------------------------------------------------------------
// Seq2Seq LSTM (2-layer enc + 2-layer autoregressive dec), B=256,H=512,T=288.
// Cooperative persistent kernel; bf16 MFMA 16x16x32 w/ fp32 accum.
// R11: proven primitives ONLY (plain h loads/stores, R4/R7 rel/acq-RMW
// barrier). Structural change: 64 blocks x 1024 threads.
//   - block = one 16-unit u-tile x all 256 batches (16 waves = 16 b-tiles).
//     blocks 0..31 = layer0 u-tiles, 32..63 = layer1 u-tiles.
//   - weight slices staged ONCE into LDS (2 x 64KB, XOR-swizzled, dynamic),
//     restaged at enc->dec. Weights leave the L2/coherence path entirely.
//   - barrier: ONE global counter, release-RMW arrival + relaxed-RMW poll +
//     acquire load (the exact R4/R6/R7-proven primitive). 64 blocks
//     => 8 wbL2 + 8 invL2 per XCD per phase instead of 32+32 (the theory
//     under test: serialized per-block cache-maintenance ops are the
//     ~22us/phase floor).
// ---------------------------------------------------------------------------

typedef __attribute__((ext_vector_type(8))) short bfx8;   // 8 bf16 (4 VGPRs)
typedef __attribute__((ext_vector_type(4))) float fx4;

#define NBLK 64
#define NTHR 1024
#define BH   (256*512)
#define SLICE 32768                          // 64 rows x 512 elems (bf16)

__device__ __forceinline__ unsigned short f2bf(float f){
  unsigned u = __float_as_uint(f);
  u += 0x7FFFu + ((u >> 16) & 1u);          // RNE
  return (unsigned short)(u >> 16);
}
__device__ __forceinline__ float bf2f(unsigned short b){
  return __uint_as_float(((unsigned)b) << 16);
}
__device__ __forceinline__ float sigm(float x){ return 1.0f/(1.0f + __expf(-x)); }
__device__ __forceinline__ float tanhf_(float x){
  x = fminf(12.0f, fmaxf(-12.0f, x));
  float e = __expf(2.0f*x);
  return (e - 1.0f)/(e + 1.0f);
}

// Global barrier (R4/R6/R7-proven primitive): release RMW publishes this
// block's h (vmcnt drained by __syncthreads); relaxed RMW poll (coherent);
// acquire load invalidates so subsequent plain h loads are fresh.
__device__ __forceinline__ void gridbar(unsigned* cnt, unsigned target){
  __syncthreads();
  if (threadIdx.x == 0){
    __hip_atomic_fetch_add(cnt, 1u, __ATOMIC_RELEASE, __HIP_MEMORY_SCOPE_AGENT);
    while (__hip_atomic_fetch_add(cnt, 0u, __ATOMIC_RELAXED,
                                  __HIP_MEMORY_SCOPE_AGENT) < target)
      __builtin_amdgcn_s_sleep(4);
    (void)__hip_atomic_load(cnt, __ATOMIC_ACQUIRE, __HIP_MEMORY_SCOPE_AGENT);
  }
  __syncthreads();
}

// Stage one 64-row x 512-elem weight slice (gates x u-tile) into LDS with an
// XOR swizzle: elem (row,k) -> row*512 + (k ^ ((row&31)<<3)). Keeps 16B
// groups contiguous; read pattern lands 2-way bank aliasing (free, m136).
__device__ __forceinline__ void stageW(uint16_t* s, const uint16_t* W, int u0){
  for (int c = threadIdx.x; c < 4096; c += NTHR){
    int row = c >> 6, kq = c & 63;
    int gate = row >> 4, uc = row & 15;
    const uint16_t* src = W + ((size_t)((gate << 9) + u0 + uc))*512 + kq*8;
    int dst = row*512 + ((kq*8) ^ ((row & 31) << 3));
    *(uint4*)(s + dst) = *(const uint4*)src;
  }
}

// K=512 accumulate: A rows from h (plain global loads), W rows from LDS.
__device__ __forceinline__ void accLDS(fx4* acc, const uint16_t* hrow,
                                       const uint16_t* sBase, int col, int quad){
  #pragma unroll
  for (int kc = 0; kc < 16; ++kc){
    bfx8 af = *(const bfx8*)(hrow + kc*32);
    #pragma unroll
    for (int gg = 0; gg < 4; ++gg){
      int row = gg*16 + col;
      int k = quad*8 + kc*32;
      const bfx8* wp = (const bfx8*)(sBase + row*512 + (k ^ ((row & 31) << 3)));
      acc[gg] = __builtin_amdgcn_mfma_f32_16x16x32_bf16(af, *wp, acc[gg], 0, 0, 0);
    }
  }
}

// LSTM pointwise: c in registers (wave-private), h store to global (plain).
__device__ __forceinline__ void pointwise(fx4* acc, fx4& creg, int bq, int u,
                                          uint16_t* hout){
  #pragma unroll
  for (int r = 0; r < 4; ++r){
    int b = bq + r;
    float iv = sigm(acc[0][r]);
    float fv = sigm(acc[1][r]);
    float gv = tanhf_(acc[2][r]);
    float ov = sigm(acc[3][r]);
    float cn = fv * creg[r] + iv * gv;
    creg[r] = cn;
    hout[b*512 + u] = f2bf(ov * tanhf_(cn));
  }
}

__global__ void __launch_bounds__(NTHR)
seq2seq_main(const uint16_t* __restrict__ Whh0e, const uint16_t* __restrict__ Wih1e,
             const uint16_t* __restrict__ Whh1e, const uint16_t* __restrict__ Whh0d,
             const uint16_t* __restrict__ Wih1d, const uint16_t* __restrict__ Whh1d,
             const uint16_t* __restrict__ Wy,
             const float* __restrict__ E0e, const float* __restrict__ E0d,
             const float* __restrict__ b1e, const float* __restrict__ b1d,
             const float* __restrict__ wcol0,
             uint16_t* h0buf, uint16_t* h1buf,
             const float* __restrict__ xh, const float* __restrict__ xf,
             const float* __restrict__ y0v,
             const float* __restrict__ encWih0, const float* __restrict__ decWih0,
             const float* __restrict__ projW, const float* __restrict__ projB,
             float* out, unsigned* cnt)
{
  extern __shared__ uint16_t sW[];           // 2 slices x 32768 elems (128KB)
  const int tid  = threadIdx.x;
  const int lane = tid & 63;
  const int wvi  = tid >> 6;                 // wave in block = batch tile 0..15
  const bool isL0 = (blockIdx.x < 32);
  const int ut   = blockIdx.x & 31;          // u-tile 0..31
  const int col  = lane & 15;
  const int quad = lane >> 4;
  const int b0 = wvi << 4;
  const int u0 = ut << 4;
  const int u  = u0 + col;
  const int bq = b0 + (quad << 2);
  unsigned gen = 0;
  fx4 creg = {0.f,0.f,0.f,0.f};

  uint16_t *h0A = h0buf, *h0B = h0buf + BH;
  uint16_t *h1A = h1buf, *h1B = h1buf + BH;

  auto encCompute = [&](int tt, const uint16_t* h0c, uint16_t* h0n){
    fx4 acc[4];
    #pragma unroll
    for (int gg = 0; gg < 4; ++gg){
      int j = (gg << 9) + u;
      #pragma unroll
      for (int r = 0; r < 4; ++r) acc[gg][r] = E0e[(size_t)(bq + r)*2048 + j];
    }
    accLDS(acc, h0c + (b0 + col)*512 + quad*8, sW, col, quad);
    float xv[4][8];
    #pragma unroll
    for (int r = 0; r < 4; ++r){
      const float* xr = xh + ((size_t)(bq + r)*288 + tt)*8;
      #pragma unroll
      for (int kk = 0; kk < 8; ++kk) xv[r][kk] = xr[kk];
    }
    #pragma unroll
    for (int gg = 0; gg < 4; ++gg){
      const float* wr = encWih0 + (size_t)((gg << 9) + u)*24;
      #pragma unroll
      for (int kk = 0; kk < 8; ++kk){
        float w = wr[kk];
        #pragma unroll
        for (int r = 0; r < 4; ++r) acc[gg][r] += w * xv[r][kk];
      }
    }
    pointwise(acc, creg, bq, u, h0n);
  };

  auto decCompute = [&](int tt, const uint16_t* h0c, const uint16_t* h1c,
                        uint16_t* h0n){
    fx4 acc[4];
    #pragma unroll
    for (int gg = 0; gg < 4; ++gg){
      int j = (gg << 9) + u;
      #pragma unroll
      for (int r = 0; r < 4; ++r) acc[gg][r] = E0d[(size_t)(bq + r)*2048 + j];
    }
    accLDS(acc, h0c + (b0 + col)*512 + quad*8, sW, col, quad);
    if (tt > 0)
      accLDS(acc, h1c + (b0 + col)*512 + quad*8, sW + SLICE, col, quad);
    float s[4];
    #pragma unroll
    for (int r = 0; r < 4; ++r) s[r] = (tt == 0) ? y0v[bq + r] : projB[0];
    #pragma unroll
    for (int gg = 0; gg < 4; ++gg){
      float w = wcol0[(gg << 9) + u];
      #pragma unroll
      for (int r = 0; r < 4; ++r) acc[gg][r] += w * s[r];
    }
    float xv[4][6];
    #pragma unroll
    for (int r = 0; r < 4; ++r){
      const float* xr = xf + ((size_t)(bq + r)*288 + tt)*6;
      #pragma unroll
      for (int kk = 0; kk < 6; ++kk) xv[r][kk] = xr[kk];
    }
    #pragma unroll
    for (int gg = 0; gg < 4; ++gg){
      const float* wr = decWih0 + (size_t)((gg << 9) + u)*23 + 1;
      #pragma unroll
      for (int kk = 0; kk < 6; ++kk){
        float w = wr[kk];
        #pragma unroll
        for (int r = 0; r < 4; ++r) acc[gg][r] += w * xv[r][kk];
      }
    }
    pointwise(acc, creg, bq, u, h0n);
  };

  auto l1Compute = [&](const float* b1, const uint16_t* h1c,
                       const uint16_t* h0n, uint16_t* h1n){
    fx4 acc[4];
    #pragma unroll
    for (int gg = 0; gg < 4; ++gg){
      float bb = b1[(gg << 9) + u];
      #pragma unroll
      for (int r = 0; r < 4; ++r) acc[gg][r] = bb;
    }
    accLDS(acc, h1c + (b0 + col)*512 + quad*8, sW, col, quad);
    accLDS(acc, h0n + (b0 + col)*512 + quad*8, sW + SLICE, col, quad);
    pointwise(acc, creg, bq, u, h1n);
  };

  // emitY: blocks 32..47, wave wvi handles row (blk-32)*16 + wvi.
  auto emitY = [&](const uint16_t* h1cur, int tt){
    int b = ((int)blockIdx.x - 32)*16 + wvi;
    const uint16_t* hr = h1cur + b*512 + lane*8;
    const float* pw = projW + lane*8;
    float part = 0.f;
    #pragma unroll
    for (int kk = 0; kk < 8; ++kk) part += bf2f(hr[kk]) * pw[kk];
    #pragma unroll
    for (int off = 32; off > 0; off >>= 1) part += __shfl_down(part, off);
    if (lane == 0) out[(size_t)b*288 + tt] = part + projB[0];
  };

  // ---- stage encoder weight slices into LDS (once) ----
  if (isL0){
    stageW(sW, Whh0e, u0);
  } else {
    stageW(sW, Whh1e, u0);
    stageW(sW + SLICE, Wih1e, u0);
  }
  __syncthreads();

  // ---- prologue: enc L0 t=0 (h_{-1}=0 via memset) ----
  if (isL0) encCompute(0, h0A, h0B);
  gridbar(cnt, (++gen)*NBLK);
  { uint16_t* t_ = h0A; h0A = h0B; h0B = t_; }   // h0A = h0_0

  // ---- encoder: 1 barrier/step; L1_t || L0_{t+1} ----
  #pragma unroll 1
  for (int t = 0; t < 288; ++t){
    if (isL0){
      if (t < 287) encCompute(t + 1, h0A, h0B);
    } else {
      l1Compute(b1e, h1A, h0A, h1B);
    }
    gridbar(cnt, (++gen)*NBLK);
    { uint16_t* t_ = h1A; h1A = h1B; h1B = t_; }
    if (t < 287){ uint16_t* t_ = h0A; h0A = h0B; h0B = t_; }
  }
  // h0A = h0_287, h1A = h1_287; c continues into decoder.

  // ---- restage decoder weight slices (LDS is block-private; safe after
  //      the last gridbar's __syncthreads) ----
  if (isL0){
    stageW(sW, Whh0d, u0);
    stageW(sW + SLICE, Wy, u0);
  } else {
    stageW(sW, Whh1d, u0);
    stageW(sW + SLICE, Wih1d, u0);
  }
  __syncthreads();

  // ---- decoder: 2 barriers/step ----
  #pragma unroll 1
  for (int t = 0; t < 288; ++t){
    if (isL0){
      decCompute(t, h0A, h1A, h0B);
    } else if (blockIdx.x < 48 && t > 0){
      emitY(h1A, t - 1);
    }
    gridbar(cnt, (++gen)*NBLK);
    if (!isL0){
      l1Compute(b1d, h1A, h0B, h1B);
    }
    gridbar(cnt, (++gen)*NBLK);
    { uint16_t* t_ = h0A; h0A = h0B; h0B = t_; }
    { uint16_t* t_ = h1A; h1A = h1B; h1B = t_; }
  }

  // final y_287
  if (!isL0 && blockIdx.x < 48) emitY(h1A, 287);
}

// ---------------- prep: bf16 weights, Wy fold, emb+bias fold ----------------
#define PREP_S 1048576
#define PREP_TOTAL (8*PREP_S + 6144)

__global__ void __launch_bounds__(256)
prep_kernel(const float* __restrict__ encWih0, const float* __restrict__ encWhh0,
            const float* __restrict__ encWih1, const float* __restrict__ encWhh1,
            const float* __restrict__ decWih0, const float* __restrict__ decWhh0,
            const float* __restrict__ decWih1, const float* __restrict__ decWhh1,
            const float* __restrict__ encbih0, const float* __restrict__ encbhh0,
            const float* __restrict__ encbih1, const float* __restrict__ encbhh1,
            const float* __restrict__ decbih0, const float* __restrict__ decbhh0,
            const float* __restrict__ decbih1, const float* __restrict__ decbhh1,
            const float* __restrict__ projW, const float* __restrict__ emb,
            const int* __restrict__ turb,
            uint16_t* Whh0e, uint16_t* Wih1e, uint16_t* Whh1e,
            uint16_t* Whh0d, uint16_t* Wih1d, uint16_t* Whh1d, uint16_t* Wy,
            float* E0e, float* E0d, float* b1e, float* b1d, float* wcol0)
{
  int i = blockIdx.x*256 + threadIdx.x;
  if (i >= PREP_TOTAL) return;
  if (i < 6*PREP_S){
    int w = i >> 20, r = i & (PREP_S - 1);
    const float* src = (w==0)?encWhh0:(w==1)?encWih1:(w==2)?encWhh1:
                       (w==3)?decWhh0:(w==4)?decWih1:decWhh1;
    uint16_t* dst = (w==0)?Whh0e:(w==1)?Wih1e:(w==2)?Whh1e:
                    (w==3)?Whh0d:(w==4)?Wih1d:Whh1d;
    dst[r] = f2bf(src[r]);
  } else if (i < 7*PREP_S){
    int r = i - 6*PREP_S; int j = r >> 9, kk = r & 511;
    Wy[r] = f2bf(decWih0[(size_t)j*23] * projW[kk]);
  } else if (i < 7*PREP_S + 524288){
    int r = i - 7*PREP_S; int b = r >> 11, j = r & 2047;
    float s = encbih0[j] + encbhh0[j];
    const float* e = emb + (size_t)turb[b]*16;
    const float* wr = encWih0 + (size_t)j*24 + 8;
    #pragma unroll
    for (int m = 0; m < 16; ++m) s += e[m]*wr[m];
    E0e[r] = s;
  } else if (i < 8*PREP_S){
    int r = i - 7*PREP_S - 524288; int b = r >> 11, j = r & 2047;
    float s = decbih0[j] + decbhh0[j];
    const float* e = emb + (size_t)turb[b]*16;
    const float* wr = decWih0 + (size_t)j*23 + 7;
    #pragma unroll
    for (int m = 0; m < 16; ++m) s += e[m]*wr[m];
    E0d[r] = s;
  } else {
    int r = i - 8*PREP_S;
    if (r < 2048)      b1e[r] = encbih1[r] + encbhh1[r];
    else if (r < 4096){ int j = r - 2048; b1d[j] = decbih1[j] + decbhh1[j]; }
    else              { int j = r - 4096; wcol0[j] = decWih0[(size_t)j*23]; }
  }
}

// ---------------------------------------------------------------------------
extern "C" void kernel_launch(void* const* d_in, const int* in_sizes, int n_in,
                              void* d_out, int out_size, void* d_ws, size_t ws_size,
                              hipStream_t stream)
{
  const float* xh      = (const float*)d_in[0];
  const float* xf      = (const float*)d_in[1];
  const float* y0v     = (const float*)d_in[2];
  const int*   turb    = (const int*)d_in[3];
  const float* emb     = (const float*)d_in[5];
  const float* encWih0 = (const float*)d_in[6];
  const float* encWhh0 = (const float*)d_in[7];
  const float* encbih0 = (const float*)d_in[8];
  const float* encbhh0 = (const float*)d_in[9];
  const float* encWih1 = (const float*)d_in[10];
  const float* encWhh1 = (const float*)d_in[11];
  const float* encbih1 = (const float*)d_in[12];
  const float* encbhh1 = (const float*)d_in[13];
  const float* decWih0 = (const float*)d_in[14];
  const float* decWhh0 = (const float*)d_in[15];
  const float* decbih0 = (const float*)d_in[16];
  const float* decbhh0 = (const float*)d_in[17];
  const float* decWih1 = (const float*)d_in[18];
  const float* decWhh1 = (const float*)d_in[19];
  const float* decbih1 = (const float*)d_in[20];
  const float* decbhh1 = (const float*)d_in[21];
  const float* projW   = (const float*)d_in[22];
  const float* projB   = (const float*)d_in[23];
  float* out = (float*)d_out;

  char* ws = (char*)d_ws;
  constexpr size_t SZW = (size_t)2048*512*2;
  constexpr size_t OFF_Whh0e = 0;
  constexpr size_t OFF_Wih1e = SZW;
  constexpr size_t OFF_Whh1e = 2*SZW;
  constexpr size_t OFF_Whh0d = 3*SZW;
  constexpr size_t OFF_Wih1d = 4*SZW;
  constexpr size_t OFF_Whh1d = 5*SZW;
  constexpr size_t OFF_Wy    = 6*SZW;
  constexpr size_t OFF_E0e   = 7*SZW;
  constexpr size_t OFF_E0d   = OFF_E0e + 2097152;
  constexpr size_t OFF_b1e   = OFF_E0d + 2097152;
  constexpr size_t OFF_b1d   = OFF_b1e + 8192;
  constexpr size_t OFF_wcol0 = OFF_b1d + 8192;
  constexpr size_t OFF_h0    = OFF_wcol0 + 8192;
  constexpr size_t OFF_h1    = OFF_h0 + 524288;
  constexpr size_t OFF_cnt   = OFF_h1 + 524288;
  constexpr size_t ZERO_BYTES = 2*524288 + 64;    // h ping-pongs + counter

  uint16_t* Whh0e = (uint16_t*)(ws + OFF_Whh0e);
  uint16_t* Wih1e = (uint16_t*)(ws + OFF_Wih1e);
  uint16_t* Whh1e = (uint16_t*)(ws + OFF_Whh1e);
  uint16_t* Whh0d = (uint16_t*)(ws + OFF_Whh0d);
  uint16_t* Wih1d = (uint16_t*)(ws + OFF_Wih1d);
  uint16_t* Whh1d = (uint16_t*)(ws + OFF_Whh1d);
  uint16_t* Wyp   = (uint16_t*)(ws + OFF_Wy);
  float* E0e   = (float*)(ws + OFF_E0e);
  float* E0d   = (float*)(ws + OFF_E0d);
  float* b1e   = (float*)(ws + OFF_b1e);
  float* b1d   = (float*)(ws + OFF_b1d);
  float* wcol0 = (float*)(ws + OFF_wcol0);
  uint16_t* h0p = (uint16_t*)(ws + OFF_h0);
  uint16_t* h1p = (uint16_t*)(ws + OFF_h1);
  unsigned* cntp = (unsigned*)(ws + OFF_cnt);

  // Opt-in to 128KB dynamic LDS (idempotent; not a stream op, capture-safe).
  hipFuncSetAttribute((const void*)seq2seq_main,
                      hipFuncAttributeMaxDynamicSharedMemorySize, 131072);

  hipMemsetAsync(ws + OFF_h0, 0, ZERO_BYTES, stream);

  prep_kernel<<<dim3((PREP_TOTAL + 255)/256), dim3(256), 0, stream>>>(
      encWih0, encWhh0, encWih1, encWhh1, decWih0, decWhh0, decWih1, decWhh1,
      encbih0, encbhh0, encbih1, encbhh1, decbih0, decbhh0, decbih1, decbhh1,
      projW, emb, turb,
      Whh0e, Wih1e, Whh1e, Whh0d, Wih1d, Whh1d, Wyp,
      E0e, E0d, b1e, b1d, wcol0);

  const uint16_t* cWhh0e = Whh0e; const uint16_t* cWih1e = Wih1e;
  const uint16_t* cWhh1e = Whh1e; const uint16_t* cWhh0d = Whh0d;
  const uint16_t* cWih1d = Wih1d; const uint16_t* cWhh1d = Whh1d;
  const uint16_t* cWy = Wyp;
  const float* cE0e = E0e; const float* cE0d = E0d;
  const float* cb1e = b1e; const float* cb1d = b1d; const float* cwcol0 = wcol0;

  void* kargs[] = {
    (void*)&cWhh0e, (void*)&cWih1e, (void*)&cWhh1e, (void*)&cWhh0d,
    (void*)&cWih1d, (void*)&cWhh1d, (void*)&cWy,
    (void*)&cE0e, (void*)&cE0d, (void*)&cb1e, (void*)&cb1d, (void*)&cwcol0,
    (void*)&h0p, (void*)&h1p,
    (void*)&xh, (void*)&xf, (void*)&y0v,
    (void*)&encWih0, (void*)&decWih0, (void*)&projW, (void*)&projB,
    (void*)&out, (void*)&cntp
  };
  hipLaunchCooperativeKernel((void*)seq2seq_main, dim3(NBLK), dim3(NTHR),
                             kargs, 131072, stream);
}